// Round 4
// baseline (14.929 us; speedup 1.0000x reference)
//
#include <hip/hip_runtime.h>

#define BN_EPS 1e-3f
#define RPB   8      // output rows per block (1024 threads / 128 lanes-per-row)
#define MAXN  512
#define MAXF  64

// Single-launch fused kernel, no grid sync, 1024 threads/block for occupancy.
// Block = (batch b, 8 consecutive output rows i0..i0+7).
//   stage 1: per-channel BN constants -> LDS
//   stage 2a: Sj_l[0..N-1] for batch b (2 threads per row, float4 feat loads, L2-hit)
//   stage 2b: Si_l[0..7]   for own rows (wave-per-row shuffle reduce)
//   stage 3: out[b,i,j] = relu(adj*inv0+b0)*w0 + Si_l[i-i0] + Sj_l[j] + cb
//            one float4 per thread, coalesced.
__global__ __launch_bounds__(1024) void fused_kernel(
    const float* __restrict__ feat,   // [B,N,F]
    const float* __restrict__ adj,    // [B,N,N]
    const float* __restrict__ gamma,
    const float* __restrict__ beta,
    const float* __restrict__ mean,
    const float* __restrict__ var,
    const float* __restrict__ w,
    const float* __restrict__ conv_b,
    float* __restrict__ out,
    int N, int F)
{
    __shared__ float sInvI[MAXF], sBi[MAXF], sWi[MAXF];
    __shared__ float sInvJ[MAXF], sBj[MAXF], sWj[MAXF];
    __shared__ float Sj_l[MAXN];
    __shared__ float Si_l[RPB];

    const int tid = threadIdx.x;
    const int bpb = N / RPB;                      // blocks per batch
    const int b   = blockIdx.x / bpb;
    const int i0  = (blockIdx.x - b * bpb) * RPB;

    // ---- stage 1: BN/conv per-channel constants ----
    if (tid < F) {
        const int ci = 1 + tid, cj = 1 + F + tid;
        const float gi = gamma[ci] * rsqrtf(var[ci] + BN_EPS);
        sInvI[tid] = gi;
        sBi[tid]   = beta[ci] - mean[ci] * gi;
        sWi[tid]   = w[ci];
        const float gj = gamma[cj] * rsqrtf(var[cj] + BN_EPS);
        sInvJ[tid] = gj;
        sBj[tid]   = beta[cj] - mean[cj] * gj;
        sWj[tid]   = w[cj];
    }
    __syncthreads();

    const float* fb = feat + (long long)b * N * F;
    const int f4n = F >> 2;                       // float4s per feature row (16)
    const int h4  = f4n >> 1;                     // per half-thread (8)

    // ---- stage 2a: Sj for ALL rows of this batch (2 threads per row) ----
    {
        const int row  = tid >> 1;                // 0..511 (N rows)
        const int half = tid & 1;
        if (row < N) {
            const float4* fr = reinterpret_cast<const float4*>(fb + (long long)row * F);
            float acc = 0.f;
            #pragma unroll 8
            for (int k = 0; k < h4; ++k) {
                const int f4 = half * h4 + k;
                const float4 x  = fr[f4];
                const float4 iv = reinterpret_cast<const float4*>(sInvJ)[f4];
                const float4 bb = reinterpret_cast<const float4*>(sBj)[f4];
                const float4 ww = reinterpret_cast<const float4*>(sWj)[f4];
                acc += fmaxf(fmaf(x.x, iv.x, bb.x), 0.f) * ww.x;
                acc += fmaxf(fmaf(x.y, iv.y, bb.y), 0.f) * ww.y;
                acc += fmaxf(fmaf(x.z, iv.z, bb.z), 0.f) * ww.z;
                acc += fmaxf(fmaf(x.w, iv.w, bb.w), 0.f) * ww.w;
            }
            acc += __shfl_down(acc, 1, 64);
            if (half == 0) Sj_l[row] = acc;
        }
    }

    // ---- stage 2b: Si for own RPB rows (wave-per-row, lane = feature) ----
    {
        const int wv = tid >> 6, ln = tid & 63;
        if (wv < RPB) {
            const int r = i0 + wv;
            float v = 0.f;
            if (ln < F) {
                const float x = fb[(long long)r * F + ln];
                v = fmaxf(fmaf(x, sInvI[ln], sBi[ln]), 0.f) * sWi[ln];
            }
            #pragma unroll
            for (int off = 32; off > 0; off >>= 1)
                v += __shfl_down(v, off, 64);
            if (ln == 0) Si_l[wv] = v;
        }
    }
    __syncthreads();

    // ---- stage 3: elementwise output over own 8 adjacency rows ----
    const float inv0 = gamma[0] * rsqrtf(var[0] + BN_EPS);
    const float b0   = beta[0] - mean[0] * inv0;
    const float w0   = w[0];
    const float cb   = conv_b[0];

    const int n4   = N >> 2;                       // 128
    const int il   = tid >> 7;                     // 0..7: local row
    const int l128 = tid & 127;
    const long long rowbase = ((long long)b * N + i0 + il) * N;
    const float4* arow = reinterpret_cast<const float4*>(adj + rowbase);
    float4*       orow = reinterpret_cast<float4*>(out + rowbase);
    const float4* sj4  = reinterpret_cast<const float4*>(Sj_l);
    const float   si   = Si_l[il] + cb;

    for (int j4 = l128; j4 < n4; j4 += 128) {
        const float4 a = arow[j4];
        const float4 s = sj4[j4];
        float4 r;
        r.x = fmaxf(fmaf(a.x, inv0, b0), 0.f) * w0 + si + s.x;
        r.y = fmaxf(fmaf(a.y, inv0, b0), 0.f) * w0 + si + s.y;
        r.z = fmaxf(fmaf(a.z, inv0, b0), 0.f) * w0 + si + s.z;
        r.w = fmaxf(fmaf(a.w, inv0, b0), 0.f) * w0 + si + s.w;
        orow[j4] = r;
    }
}

extern "C" void kernel_launch(void* const* d_in, const int* in_sizes, int n_in,
                              void* d_out, int out_size, void* d_ws, size_t ws_size,
                              hipStream_t stream) {
    const float* feat  = (const float*)d_in[0];   // [B,N,F]
    const float* adj   = (const float*)d_in[1];   // [B,N,N]
    const float* gamma = (const float*)d_in[2];   // [C]
    const float* beta  = (const float*)d_in[3];
    const float* mean  = (const float*)d_in[4];
    const float* var   = (const float*)d_in[5];
    const float* w     = (const float*)d_in[6];
    const float* cb    = (const float*)d_in[7];   // [1]

    const int C  = in_sizes[2];
    const int F  = (C - 1) / 2;                   // 64
    const int BN = in_sizes[0] / F;               // B*N = 2048
    const long long total = in_sizes[1];          // B*N*N
    const int N  = (int)(total / BN);             // 512
    const int B  = BN / N;                        // 4

    const int blocks = B * (N / RPB);             // 256

    fused_kernel<<<blocks, 1024, 0, stream>>>(feat, adj, gamma, beta, mean, var,
                                              w, cb, (float*)d_out, N, F);
}

// Round 5
// 11.989 us; speedup vs baseline: 1.2453x; 1.2453x over previous
//
#include <hip/hip_runtime.h>

#define BN_EPS 1e-3f

// Kernel 1: per-node partial sums, wave-per-row (lane = feature), 4 rows/block.
// Si[b*N+n] = sum_f relu(feat[b,n,f]*inv[1+f]   + bias[1+f])   * w[1+f]
// Sj[b*N+n] = sum_f relu(feat[b,n,f]*inv[1+F+f] + bias[1+F+f]) * w[1+F+f]
__global__ __launch_bounds__(256) void node_sums_kernel(
    const float* __restrict__ feat,   // [B,N,F]
    const float* __restrict__ gamma,
    const float* __restrict__ beta,
    const float* __restrict__ mean,
    const float* __restrict__ var,
    const float* __restrict__ w,
    float* __restrict__ Si,
    float* __restrict__ Sj,
    int F, int BN) {
    const int lane = threadIdx.x & 63;
    const int row  = (blockIdx.x * blockDim.x + threadIdx.x) >> 6;  // b*N + n
    if (row >= BN) return;

    const bool act = (lane < F);
    const int  fl  = act ? lane : (F - 1);
    const int  ci  = 1 + fl;
    const int  cj  = 1 + F + fl;

    const float invi = gamma[ci] * rsqrtf(var[ci] + BN_EPS);
    const float bi   = beta[ci] - mean[ci] * invi;
    const float invj = gamma[cj] * rsqrtf(var[cj] + BN_EPS);
    const float bj   = beta[cj] - mean[cj] * invj;

    const float x = feat[(long long)row * F + fl];
    float vi = act ? fmaxf(fmaf(x, invi, bi), 0.0f) * w[ci] : 0.0f;
    float vj = act ? fmaxf(fmaf(x, invj, bj), 0.0f) * w[cj] : 0.0f;

    #pragma unroll
    for (int off = 32; off > 0; off >>= 1) {
        vi += __shfl_down(vi, off, 64);
        vj += __shfl_down(vj, off, 64);
    }
    if (lane == 0) {
        Si[row] = vi;
        Sj[row] = vj;
    }
}

// Kernel 2: out[b,i,j] = relu(adj*inv0 + bias0)*w0 + Si[b*N+i] + Sj[b*N+j] + cb
// One float4 per thread over flat [B*N*N]; N % 4 == 0. With 256-thread blocks,
// each wave covers exactly half an output row -> `row` is wave-uniform.
__global__ __launch_bounds__(256) void out_kernel(
    const float* __restrict__ adj,
    const float* __restrict__ Si,
    const float* __restrict__ Sj,
    float* __restrict__ out,
    const float* __restrict__ gamma,
    const float* __restrict__ beta,
    const float* __restrict__ mean,
    const float* __restrict__ var,
    const float* __restrict__ w,
    const float* __restrict__ conv_b,
    int N, int total4) {
    const int t = blockIdx.x * blockDim.x + threadIdx.x;
    if (t >= total4) return;

    const float inv0 = gamma[0] * rsqrtf(var[0] + BN_EPS);
    const float b0   = beta[0] - mean[0] * inv0;
    const float w0   = w[0];
    const float cb   = conv_b[0];

    const float4 a = reinterpret_cast<const float4*>(adj)[t];

    const int idx = t * 4;                       // flat index into [B*N*N]
    const int row = __builtin_amdgcn_readfirstlane(idx / N);  // wave-uniform: b*N+i
    const int b   = row / N;                     // batch
    const int j0  = idx - row * N;

    const float  si = Si[row] + cb;              // scalar (SGPR) load
    const float4 s  = *reinterpret_cast<const float4*>(Sj + b * N + j0);

    float4 r;
    r.x = fmaxf(fmaf(a.x, inv0, b0), 0.0f) * w0 + si + s.x;
    r.y = fmaxf(fmaf(a.y, inv0, b0), 0.0f) * w0 + si + s.y;
    r.z = fmaxf(fmaf(a.z, inv0, b0), 0.0f) * w0 + si + s.z;
    r.w = fmaxf(fmaf(a.w, inv0, b0), 0.0f) * w0 + si + s.w;

    reinterpret_cast<float4*>(out)[t] = r;
}

extern "C" void kernel_launch(void* const* d_in, const int* in_sizes, int n_in,
                              void* d_out, int out_size, void* d_ws, size_t ws_size,
                              hipStream_t stream) {
    const float* feat  = (const float*)d_in[0];   // [B,N,F]
    const float* adj   = (const float*)d_in[1];   // [B,N,N]
    const float* gamma = (const float*)d_in[2];   // [C]
    const float* beta  = (const float*)d_in[3];
    const float* mean  = (const float*)d_in[4];
    const float* var   = (const float*)d_in[5];
    const float* w     = (const float*)d_in[6];
    const float* cb    = (const float*)d_in[7];   // [1]

    const int C  = in_sizes[2];
    const int F  = (C - 1) / 2;                   // 64
    const int BN = in_sizes[0] / F;               // B*N = 2048
    const long long total = in_sizes[1];          // B*N*N
    const int N  = (int)(total / BN);             // 512

    float* Si = (float*)d_ws;                     // BN floats
    float* Sj = Si + BN;                          // BN floats

    // kernel 1: 4 wave-rows per 256-thread block
    const int blocks1 = (BN * 64 + 255) / 256;    // 512
    node_sums_kernel<<<blocks1, 256, 0, stream>>>(feat, gamma, beta, mean, var,
                                                  w, Si, Sj, F, BN);

    const int total4  = (int)(total / 4);
    const int blocks2 = (total4 + 255) / 256;     // 2048
    out_kernel<<<blocks2, 256, 0, stream>>>(adj, Si, Sj, (float*)d_out,
                                            gamma, beta, mean, var, w, cb,
                                            N, total4);
}